// Round 7
// baseline (2278.251 us; speedup 1.0000x reference)
//
#include <hip/hip_runtime.h>
#include <cstdint>
#include <cstddef>

#define TT 2048
#define BB 4
#define HDIM 512
#define NH 4
#define LAYERS 4
#define WINDOW 606

#define PLANE_QK 4194304ull   // 16*2048*128
#define PLANE_X  4194304ull   // 8192*512
#define PLANE_FF 16777216ull  // 8192*2048

typedef __attribute__((ext_vector_type(8))) short bf16x8s;
typedef __attribute__((ext_vector_type(4))) float f32x4;

// ---------------- helpers ----------------
__device__ __forceinline__ float wred_sum(float v) {
#pragma unroll
  for (int off = 32; off; off >>= 1) v += __shfl_xor(v, off, 64);
  return v;
}
__device__ __forceinline__ float gelu_exact(float x) {
  return 0.5f * x * (1.0f + erff(x * 0.70710678118654752f));
}
__device__ __forceinline__ ushort bf16_rne(float v) {
  uint32_t u = __float_as_uint(v);
  u += 0x7FFFu + ((u >> 16) & 1u);
  return (ushort)(u >> 16);
}
__device__ __forceinline__ void split3(float v, ushort& h, ushort& l) {
  h = bf16_rne(v);
  const float hf = __uint_as_float(((uint32_t)h) << 16);
  l = bf16_rne(v - hf);
}
__device__ __forceinline__ void gld_lds16(const void* g, void* l) {
  __builtin_amdgcn_global_load_lds(
      (const __attribute__((address_space(1))) uint32_t*)g,
      (__attribute__((address_space(3))) uint32_t*)l, 16, 0, 0);
}

// ---------------- input embed ----------------
__global__ __launch_bounds__(256) void embed_kernel(
    const float* __restrict__ u, const float* __restrict__ y,
    const float* __restrict__ W_in, const float* __restrict__ b_in,
    float* __restrict__ X, ushort* __restrict__ xp) {
  const int row = blockIdx.x;
  const int b = row >> 11;
  const int t = row & 2047;
  const int tid = threadIdx.x;
  __shared__ float ua[24];
  if (tid < 8)       ua[tid] = u[((b << 3) + tid) * TT + t];
  else if (tid < 16) ua[tid] = 0.0f;   // y_aug (phy rollout) is zeros
  else if (tid < 24) ua[tid] = (t < 30) ? y[((b << 3) + (tid - 16)) * TT + t] : 0.0f;
  __syncthreads();
#pragma unroll
  for (int c0 = 0; c0 < 2; ++c0) {
    const int c = c0 * 256 + tid;
    float s = b_in[c];
#pragma unroll
    for (int k = 0; k < 24; ++k) s += ua[k] * W_in[k * HDIM + c];
    const float dv = expf(-0.0179889460337f * (float)(c & ~1));
    const float arg = (float)t * dv;
    s += (c & 1) ? cosf(arg) : sinf(arg);
    X[(size_t)row * HDIM + c] = s;
    ushort h, l2; split3(s, h, l2);
    xp[(size_t)row * HDIM + c] = h;
    xp[PLANE_X + (size_t)row * HDIM + c] = l2;
  }
}

// ---------------- weight pack ----------------
__device__ __forceinline__ void pack_tile(float (*tile)[33],
    const float* __restrict__ W, ushort* __restrict__ Wp,
    int K, int N, int bk, int bn, int tid) {
  const int i0 = tid >> 5, j = tid & 31;
#pragma unroll
  for (int i = 0; i < 4; ++i) {
    const int kk = i0 + i * 8;
    tile[kk][j] = W[(size_t)(bk + kk) * N + bn + j];
  }
  __syncthreads();
  const size_t NK = (size_t)N * K;
#pragma unroll
  for (int i = 0; i < 4; ++i) {
    const int nn = i0 + i * 8;
    const float v = tile[j][nn];
    ushort h, l2; split3(v, h, l2);
    ushort* base = Wp + (size_t)(bn + nn) * K + bk + j;
    base[0] = h; base[NK] = l2;
  }
}

__global__ __launch_bounds__(256) void packL_kernel(
    const float* __restrict__ qkvw, const float* __restrict__ outw,
    const float* __restrict__ ff1w, ushort* __restrict__ Wp) {
  __shared__ float tile[32][33];
  int i = blockIdx.x;
  if (i < 768) {
    pack_tile(tile, qkvw, Wp, 512, 1536, (i & 15) * 32, (i >> 4) * 32, threadIdx.x);
  } else if (i < 1024) {
    i -= 768;
    pack_tile(tile, outw, Wp + 1572864, 512, 512, (i & 15) * 32, (i >> 4) * 32, threadIdx.x);
  } else {
    i -= 1024;
    pack_tile(tile, ff1w, Wp + 2097152, 512, 2048, (i & 15) * 32, (i >> 4) * 32, threadIdx.x);
  }
}

__global__ __launch_bounds__(256) void packF_kernel(
    const float* __restrict__ ff2w, ushort* __restrict__ Wp) {
  __shared__ float tile[32][33];
  const int i = blockIdx.x;
  pack_tile(tile, ff2w, Wp, 2048, 512, (i & 63) * 32, (i >> 6) * 32, threadIdx.x);
}

__global__ __launch_bounds__(256) void packH_kernel(
    const float* __restrict__ xm1w, const float* __restrict__ me2w,
    ushort* __restrict__ Wp) {
  __shared__ float tile[32][33];
  int i = blockIdx.x;
  if (i < 256) pack_tile(tile, xm1w, Wp, 512, 512, (i & 15) * 32, (i >> 4) * 32, threadIdx.x);
  else { i -= 256; pack_tile(tile, me2w, Wp + 524288, 512, 512, (i & 15) * 32, (i >> 4) * 32, threadIdx.x); }
}

// ---------------- bf16 MFMA GEMM (3-term hi/lo split) ----------------
template <int ACT, int OUTMODE, int RM>
__global__ __launch_bounds__(256) void gemm_mfma(
    const ushort* __restrict__ Ah, const ushort* __restrict__ Al,
    const ushort* __restrict__ Bh, const ushort* __restrict__ Bl,
    const float* __restrict__ bias,
    float* __restrict__ C, ushort* __restrict__ Cp, size_t cplane,
    ushort* __restrict__ Wq, int M, int N, int K) {
  constexpr int IA = RM / 32;
  constexpr int JA = RM / 64;
  __shared__ ushort Als[RM * 32];
  __shared__ ushort Bls[4096];
  __shared__ float biasL[128];
  const int tid = threadIdx.x;
  const int bn = blockIdx.x * 128, bm = blockIdx.y * RM;
  const int w = tid >> 6, ln = tid & 63;
  const int wr = (w >> 1) * (RM / 2), wc = (w & 1) * 64;
  const int c = ln & 15, g = ln >> 4;
  if (tid < 128) biasL[tid] = bias[bn + tid];

  const int srow = tid >> 2;
  const int scol = (tid & 3) * 8;

  f32x4 acc[IA][4] = {};
#pragma unroll
  for (int term = 0; term < 3; ++term) {
    const ushort* Ag = (term == 1) ? Al : Ah;
    const ushort* Bg = (term == 2) ? Bl : Bh;
    for (int k0 = 0; k0 < K; k0 += 32) {
#pragma unroll
      for (int j = 0; j < JA; ++j) {
        const int off = j * 4096 + tid * 16;
        gld_lds16(Ag + (size_t)(bm + j * 64 + srow) * K + k0 + scol, (char*)Als + off);
      }
#pragma unroll
      for (int j = 0; j < 2; ++j) {
        const int off = j * 4096 + tid * 16;
        gld_lds16(Bg + (size_t)(bn + j * 64 + srow) * K + k0 + scol, (char*)Bls + off);
      }
      __syncthreads();
      bf16x8s fa[IA], fb[4];
#pragma unroll
      for (int i = 0; i < IA; ++i)
        fa[i] = *(const bf16x8s*)&Als[(wr + i * 16 + c) * 32 + g * 8];
#pragma unroll
      for (int i = 0; i < 4; ++i)
        fb[i] = *(const bf16x8s*)&Bls[(wc + i * 16 + c) * 32 + g * 8];
#pragma unroll
      for (int i = 0; i < IA; ++i)
#pragma unroll
        for (int j = 0; j < 4; ++j)
          acc[i][j] = __builtin_amdgcn_mfma_f32_16x16x32_bf16(fa[i], fb[j], acc[i][j], 0, 0, 0);
      __syncthreads();
    }
  }
  // Q pre-scale folds 1/sqrt(128) * log2(e) so attention can use exp2.
  const float qscale = 0.08838834764831845f * 1.44269504088896341f;
#pragma unroll
  for (int i = 0; i < IA; ++i) {
    const int grow0 = bm + wr + i * 16 + g * 4;
#pragma unroll
    for (int j = 0; j < 4; ++j) {
      const int gcol = bn + wc + j * 16 + c;
      const float bv = biasL[wc + j * 16 + c];
      if (OUTMODE == 2) {
        const int bq = grow0 >> 11, tl = grow0 & 2047;
        if (bn < 512) {            // Q: scaled, row-major [bh][t][128]
          const int hh = gcol >> 7, d = gcol & 127;
          ushort* dst = Wq + ((size_t)(bq * NH + hh) * TT + tl) * 128 + d;
#pragma unroll
          for (int r = 0; r < 4; ++r) {
            ushort h, l2; split3((acc[i][j][r] + bv) * qscale, h, l2);
            dst[(size_t)r * 128] = h;
            dst[PLANE_QK + (size_t)r * 128] = l2;
          }
        } else if (bn < 1024) {    // K: row-major [bh][t][128]
          const int hh = (gcol - 512) >> 7, d = gcol & 127;
          ushort* dst = Wq + 2 * PLANE_QK + ((size_t)(bq * NH + hh) * TT + tl) * 128 + d;
#pragma unroll
          for (int r = 0; r < 4; ++r) {
            ushort h, l2; split3(acc[i][j][r] + bv, h, l2);
            dst[(size_t)r * 128] = h;
            dst[PLANE_QK + (size_t)r * 128] = l2;
          }
        } else {                   // V: transposed [bh][d][t]
          const int hh = (gcol - 1024) >> 7, d = gcol & 127;
          ushort4 h4, l4;
          split3(acc[i][j][0] + bv, h4.x, l4.x);
          split3(acc[i][j][1] + bv, h4.y, l4.y);
          split3(acc[i][j][2] + bv, h4.z, l4.z);
          split3(acc[i][j][3] + bv, h4.w, l4.w);
          ushort* dst = Wq + 4 * PLANE_QK + ((size_t)(bq * NH + hh) * 128 + d) * TT + tl;
          *(ushort4*)dst = h4;
          *(ushort4*)(dst + PLANE_QK) = l4;
        }
      } else {
#pragma unroll
        for (int r = 0; r < 4; ++r) {
          float v = acc[i][j][r] + bv;
          if (ACT) v = gelu_exact(v);
          if (OUTMODE == 1) {
            ushort h, l2; split3(v, h, l2);
            ushort* base = Cp + (size_t)(grow0 + r) * N + gcol;
            base[0] = h; base[cplane] = l2;
          } else {
            C[(size_t)(grow0 + r) * N + gcol] = v;
          }
        }
      }
    }
  }
}

// ---------------- fp32 tiled GEMM (small shapes: xm2, me1) ----------------
template <int ACT, int PACK>
__global__ __launch_bounds__(256) void gemm_bias(
    const float* __restrict__ A, const float* __restrict__ B,
    const float* __restrict__ bias, float* __restrict__ C,
    ushort* __restrict__ Cp, size_t cplane, int M, int N, int K) {
  __shared__ float As[16][132];
  __shared__ float Bs[16][64];
  const int bm = blockIdx.y * 128;
  const int bn = blockIdx.x * 64;
  const int tid = threadIdx.x;
  const int tx = tid & 15, ty = tid >> 4;
  float acc[8][4] = {};
  for (int k0 = 0; k0 < K; k0 += 16) {
#pragma unroll
    for (int i = 0; i < 8; ++i) {
      const int idx = i * 256 + tid;
      const int m = idx >> 4, k = idx & 15;
      As[k][m] = A[(size_t)(bm + m) * K + k0 + k];
    }
#pragma unroll
    for (int i = 0; i < 4; ++i) {
      const int idx = i * 256 + tid;
      const int k = idx >> 6, n = idx & 63;
      Bs[k][n] = (bn + n < N) ? B[(size_t)(k0 + k) * N + bn + n] : 0.0f;
    }
    __syncthreads();
#pragma unroll
    for (int kk = 0; kk < 16; ++kk) {
      float a[8], bb[4];
#pragma unroll
      for (int i = 0; i < 8; ++i) a[i] = As[kk][ty * 8 + i];
#pragma unroll
      for (int j = 0; j < 4; ++j) bb[j] = Bs[kk][tx * 4 + j];
#pragma unroll
      for (int i = 0; i < 8; ++i)
#pragma unroll
        for (int j = 0; j < 4; ++j) acc[i][j] += a[i] * bb[j];
    }
    __syncthreads();
  }
#pragma unroll
  for (int i = 0; i < 8; ++i) {
    const int m = bm + ty * 8 + i;
#pragma unroll
    for (int j = 0; j < 4; ++j) {
      const int n = bn + tx * 4 + j;
      if (n < N) {
        float v = acc[i][j] + bias[n];
        if (ACT) v = gelu_exact(v);
        if (PACK) {
          ushort h, l2; split3(v, h, l2);
          ushort* base = Cp + (size_t)m * N + n;
          base[0] = h; base[cplane] = l2;
        } else {
          C[(size_t)m * N + n] = v;
        }
      }
    }
  }
}

// ---------------- barrier-free MFMA flash attention ----------------
// Each wave owns 16 queries end-to-end: swapped QK^T over both 16-k halves
// (full 32-k row stats in-register), O accumulated TRANSPOSED D[d][q] so the
// rescale is lane-uniform and V frags are contiguous loads from Vt planes.
// P regs (k in 4-chunks) -> PV B-frag (k in 8-chunks) via 16 lane shuffles.
__device__ __forceinline__ void bfrag_from_pairs(
    uint32_t P0, uint32_t P1, uint32_t P2, uint32_t P3,
    int c, int g, uint32_t w[4]) {
  const int s0 = c + 16 * ((2 * g) & 3);
  const int s1 = c + 16 * ((2 * g + 1) & 3);
  const uint32_t a0 = (uint32_t)__shfl((int)P0, s0, 64);
  const uint32_t b0 = (uint32_t)__shfl((int)P2, s0, 64);
  const uint32_t a1 = (uint32_t)__shfl((int)P1, s0, 64);
  const uint32_t b1 = (uint32_t)__shfl((int)P3, s0, 64);
  const uint32_t a2 = (uint32_t)__shfl((int)P0, s1, 64);
  const uint32_t b2 = (uint32_t)__shfl((int)P2, s1, 64);
  const uint32_t a3 = (uint32_t)__shfl((int)P1, s1, 64);
  const uint32_t b3 = (uint32_t)__shfl((int)P3, s1, 64);
  const bool lo = (g < 2);
  w[0] = lo ? a0 : b0;
  w[1] = lo ? a1 : b1;
  w[2] = lo ? a2 : b2;
  w[3] = lo ? a3 : b3;
}

__global__ __launch_bounds__(256) void attn_mfma(
    const ushort* __restrict__ QKVp, ushort* __restrict__ atp) {
  // XCD swizzle: 512 blocks, 8 XCDs -> 64 contiguous blocks (2 heads) per XCD
  const int bid = blockIdx.x;
  const int lid = (bid & 7) * 64 + (bid >> 3);
  const int qb = lid & 31;           // 32 q-blocks of 64 per head
  const int bh = lid >> 5;
  const int b = bh >> 2, hh = bh & 3;
  const int tid = threadIdx.x;
  const int w = tid >> 6, lane = tid & 63;
  const int c = lane & 15, g = lane >> 4;
  const int q0w = qb * 64 + w * 16;  // this wave's 16 queries

  const ushort* Qh = QKVp;
  const ushort* Ql = QKVp + PLANE_QK;
  const ushort* Kh = QKVp + 2 * PLANE_QK;
  const ushort* Kl = QKVp + 3 * PLANE_QK;
  const ushort* Vh = QKVp + 4 * PLANE_QK;
  const ushort* Vl = QKVp + 5 * PLANE_QK;
  const size_t qkbase = (size_t)bh * TT * 128;
  const size_t vtbase = (size_t)bh * 128 * TT;

  // Q B-frags (q = q0w + c), held for the whole kernel
  bf16x8s qfh[4], qfl[4];
  {
    const ushort* qr  = Qh + qkbase + (size_t)(q0w + c) * 128 + g * 8;
    const ushort* qr2 = Ql + qkbase + (size_t)(q0w + c) * 128 + g * 8;
#pragma unroll
    for (int kc = 0; kc < 4; ++kc) {
      qfh[kc] = *(const bf16x8s*)(qr + kc * 32);
      qfl[kc] = *(const bf16x8s*)(qr2 + kc * 32);
    }
  }

  float m_reg = -1e30f, l_reg = 0.0f;   // per-lane state for q = q0w + c
  f32x4 oacc[8] = {};                    // O^T: d = i*16 + 4g + r, q = c

  int lo_ = q0w - (WINDOW - 1); if (lo_ < 0) lo_ = 0;
  const int k_first = lo_ & ~31;
  const int k_last = (q0w + 15) & ~31;
  const int qg = q0w + c;

  for (int k0 = k_first; k0 <= k_last; k0 += 32) {
    // ---- QK^T: both 16-k halves, 3-term split ----
    f32x4 s0 = {}, s1 = {};
    {
      const ushort* k0h = Kh + qkbase + (size_t)(k0 + c) * 128 + g * 8;
      const ushort* k1h = Kh + qkbase + (size_t)(k0 + 16 + c) * 128 + g * 8;
      const ushort* k0l = Kl + qkbase + (size_t)(k0 + c) * 128 + g * 8;
      const ushort* k1l = Kl + qkbase + (size_t)(k0 + 16 + c) * 128 + g * 8;
      bf16x8s kf0h[4], kf1h[4], kf0l[4], kf1l[4];
#pragma unroll
      for (int kc = 0; kc < 4; ++kc) {
        kf0h[kc] = *(const bf16x8s*)(k0h + kc * 32);
        kf1h[kc] = *(const bf16x8s*)(k1h + kc * 32);
        kf0l[kc] = *(const bf16x8s*)(k0l + kc * 32);
        kf1l[kc] = *(const bf16x8s*)(k1l + kc * 32);
      }
#pragma unroll
      for (int kc = 0; kc < 4; ++kc) {
        s0 = __builtin_amdgcn_mfma_f32_16x16x32_bf16(kf0h[kc], qfh[kc], s0, 0, 0, 0);
        s1 = __builtin_amdgcn_mfma_f32_16x16x32_bf16(kf1h[kc], qfh[kc], s1, 0, 0, 0);
      }
#pragma unroll
      for (int kc = 0; kc < 4; ++kc) {
        s0 = __builtin_amdgcn_mfma_f32_16x16x32_bf16(kf0l[kc], qfh[kc], s0, 0, 0, 0);
        s1 = __builtin_amdgcn_mfma_f32_16x16x32_bf16(kf1l[kc], qfh[kc], s1, 0, 0, 0);
      }
#pragma unroll
      for (int kc = 0; kc < 4; ++kc) {
        s0 = __builtin_amdgcn_mfma_f32_16x16x32_bf16(kf0h[kc], qfl[kc], s0, 0, 0, 0);
        s1 = __builtin_amdgcn_mfma_f32_16x16x32_bf16(kf1h[kc], qfl[kc], s1, 0, 0, 0);
      }
    }
    // ---- mask + in-register row stats (per q = c, replicated across g) ----
    float e[8];
    float mx = -1e30f;
#pragma unroll
    for (int r = 0; r < 4; ++r) {
      const int kj0 = k0 + 4 * g + r;
      const int kj1 = kj0 + 16;
      const bool ok0 = (kj0 <= qg) && (kj0 > qg - WINDOW);
      const bool ok1 = (kj1 <= qg) && (kj1 > qg - WINDOW);
      e[r]     = ok0 ? s0[r] : -1e30f;
      e[4 + r] = ok1 ? s1[r] : -1e30f;
      mx = fmaxf(mx, fmaxf(e[r], e[4 + r]));
    }
    mx = fmaxf(mx, __shfl_xor(mx, 16, 64));
    mx = fmaxf(mx, __shfl_xor(mx, 32, 64));
    const float mn = fmaxf(m_reg, mx);
    const float rescale = exp2f(m_reg - mn);
    float ps = 0.0f;
#pragma unroll
    for (int i = 0; i < 8; ++i) {
      e[i] = (e[i] > -1e29f) ? exp2f(e[i] - mn) : 0.0f;
      ps += e[i];
    }
    ps += __shfl_xor(ps, 16, 64);
    ps += __shfl_xor(ps, 32, 64);
    l_reg = l_reg * rescale + ps;
    m_reg = mn;
#pragma unroll
    for (int i = 0; i < 8; ++i)
#pragma unroll
      for (int r = 0; r < 4; ++r) oacc[i][r] *= rescale;

    // ---- P -> PV B-frags (hi/lo), k 4-chunks -> 8-chunks via shfl ----
    ushort hh8[8], ll8[8];
#pragma unroll
    for (int i = 0; i < 8; ++i) split3(e[i], hh8[i], ll8[i]);
    const uint32_t P0h = (uint32_t)hh8[0] | ((uint32_t)hh8[1] << 16);
    const uint32_t P1h = (uint32_t)hh8[2] | ((uint32_t)hh8[3] << 16);
    const uint32_t P2h = (uint32_t)hh8[4] | ((uint32_t)hh8[5] << 16);
    const uint32_t P3h = (uint32_t)hh8[6] | ((uint32_t)hh8[7] << 16);
    const uint32_t P0l = (uint32_t)ll8[0] | ((uint32_t)ll8[1] << 16);
    const uint32_t P1l = (uint32_t)ll8[2] | ((uint32_t)ll8[3] << 16);
    const uint32_t P2l = (uint32_t)ll8[4] | ((uint32_t)ll8[5] << 16);
    const uint32_t P3l = (uint32_t)ll8[6] | ((uint32_t)ll8[7] << 16);
    union { uint32_t u[4]; bf16x8s v; } ph, pl;
    bfrag_from_pairs(P0h, P1h, P2h, P3h, c, g, ph.u);
    bfrag_from_pairs(P0l, P1l, P2l, P3l, c, g, pl.u);

    // ---- PV: O^T[d][q] += V^T frags x P frags (3-term) ----
#pragma unroll
    for (int i = 0; i < 8; ++i) {
      const ushort* va = Vh + vtbase + (size_t)(i * 16 + c) * TT + k0 + g * 8;
      const ushort* vb = Vl + vtbase + (size_t)(i * 16 + c) * TT + k0 + g * 8;
      const bf16x8s vfh = *(const bf16x8s*)va;
      const bf16x8s vfl = *(const bf16x8s*)vb;
      oacc[i] = __builtin_amdgcn_mfma_f32_16x16x32_bf16(vfh, ph.v, oacc[i], 0, 0, 0);
      oacc[i] = __builtin_amdgcn_mfma_f32_16x16x32_bf16(vfh, pl.v, oacc[i], 0, 0, 0);
      oacc[i] = __builtin_amdgcn_mfma_f32_16x16x32_bf16(vfl, ph.v, oacc[i], 0, 0, 0);
    }
  }

  // ---- normalize + 2-plane pack out (q = q0w + c, d = i*16 + 4g + r) ----
  const float li = 1.0f / l_reg;
  ushort* rowbase = atp + (size_t)(b * TT + q0w + c) * HDIM + hh * 128;
#pragma unroll
  for (int i = 0; i < 8; ++i) {
    ushort4 h4, l4;
    split3(oacc[i][0] * li, h4.x, l4.x);
    split3(oacc[i][1] * li, h4.y, l4.y);
    split3(oacc[i][2] * li, h4.z, l4.z);
    split3(oacc[i][3] * li, h4.w, l4.w);
    ushort* dst = rowbase + i * 16 + 4 * g;
    *(ushort4*)dst = h4;
    *(ushort4*)(dst + PLANE_X) = l4;
  }
}

// ---------------- residual + LayerNorm ----------------
template <int HAS_RES>
__global__ __launch_bounds__(128) void ln_kernel(
    const float* __restrict__ x, const float* __restrict__ r,
    const float* __restrict__ g, const float* __restrict__ be,
    float* __restrict__ out, ushort* __restrict__ xp) {
  const int row = blockIdx.x, tid = threadIdx.x;
  float4 v = ((const float4*)(x + (size_t)row * HDIM))[tid];
  if (HAS_RES) {
    const float4 rv = ((const float4*)(r + (size_t)row * HDIM))[tid];
    v.x += rv.x; v.y += rv.y; v.z += rv.z; v.w += rv.w;
  }
  __shared__ float red[2];
  float s = v.x + v.y + v.z + v.w;
  s = wred_sum(s);
  if ((tid & 63) == 0) red[tid >> 6] = s;
  __syncthreads();
  const float mean = (red[0] + red[1]) * (1.0f / 512.0f);
  const float dx = v.x - mean, dy = v.y - mean, dz = v.z - mean, dw = v.w - mean;
  float s2 = dx * dx + dy * dy + dz * dz + dw * dw;
  __syncthreads();
  s2 = wred_sum(s2);
  if ((tid & 63) == 0) red[tid >> 6] = s2;
  __syncthreads();
  const float var = (red[0] + red[1]) * (1.0f / 512.0f);
  const float inv = 1.0f / sqrtf(var + 1e-5f);
  const float4 gv = ((const float4*)g)[tid];
  const float4 bv = ((const float4*)be)[tid];
  float4 o;
  o.x = dx * inv * gv.x + bv.x;
  o.y = dy * inv * gv.y + bv.y;
  o.z = dz * inv * gv.z + bv.z;
  o.w = dw * inv * gv.w + bv.w;
  ((float4*)(out + (size_t)row * HDIM))[tid] = o;
  ushort4 h4, l4;
  split3(o.x, h4.x, l4.x); split3(o.y, h4.y, l4.y);
  split3(o.z, h4.z, l4.z); split3(o.w, h4.w, l4.w);
  ushort* basep = xp + (size_t)row * HDIM + tid * 4;
  *(ushort4*)basep = h4;
  *(ushort4*)(basep + PLANE_X) = l4;
}

// ---------------- fused me3 projection + SSE loss partials ----------------
__global__ __launch_bounds__(256) void head_loss_kernel(
    const float* __restrict__ hme, const float* __restrict__ w3,
    const float* __restrict__ b3, const float* __restrict__ y,
    float* __restrict__ partials) {
  const int row = blockIdx.x;
  const int b = row >> 11, t = row & 2047;
  const int tid = threadIdx.x;
  __shared__ __align__(16) float hl[512];
  __shared__ float acc8[8];
  ((float2*)hl)[tid] = ((const float2*)(hme + (size_t)row * HDIM))[tid];
  __syncthreads();
  const int d = tid >> 5, l32 = tid & 31;
  float s = 0.0f;
  for (int k = l32; k < 512; k += 32) s += hl[k] * w3[k * 8 + d];
#pragma unroll
  for (int off = 16; off; off >>= 1) s += __shfl_xor(s, off, 64);
  if (l32 == 0) {
    const float yh = s + b3[d];
    const float diff = yh - y[((b << 3) + d) * TT + t];
    acc8[d] = diff * diff;
  }
  __syncthreads();
  if (tid == 0) {
    float tot = 0.0f;
#pragma unroll
    for (int i = 0; i < 8; ++i) tot += acc8[i];
    partials[row] = tot;
  }
}

__global__ __launch_bounds__(256) void reduce_kernel(
    const float* __restrict__ partials, float* __restrict__ out, int n) {
  float s = 0.0f;
  for (int i = threadIdx.x; i < n; i += 256) s += partials[i];
  s = wred_sum(s);
  __shared__ float red[4];
  if ((threadIdx.x & 63) == 0) red[threadIdx.x >> 6] = s;
  __syncthreads();
  if (threadIdx.x == 0) out[0] = red[0] + red[1] + red[2] + red[3];
}

// ---------------- host ----------------
extern "C" void kernel_launch(void* const* d_in, const int* in_sizes, int n_in,
                              void* d_out, int out_size, void* d_ws, size_t ws_size,
                              hipStream_t stream) {
  (void)in_sizes; (void)n_in; (void)out_size; (void)ws_size;
  const float* u     = (const float*)d_in[0];
  const float* y     = (const float*)d_in[1];
  const float* W_in  = (const float*)d_in[2];
  const float* b_in  = (const float*)d_in[3];
  const float* qkv_w = (const float*)d_in[4];
  const float* qkv_b = (const float*)d_in[5];
  const float* out_w = (const float*)d_in[6];
  const float* out_b = (const float*)d_in[7];
  const float* ff1_w = (const float*)d_in[8];
  const float* ff1_b = (const float*)d_in[9];
  const float* ff2_w = (const float*)d_in[10];
  const float* ff2_b = (const float*)d_in[11];
  const float* ln1_g = (const float*)d_in[12];
  const float* ln1_b = (const float*)d_in[13];
  const float* ln2_g = (const float*)d_in[14];
  const float* ln2_b = (const float*)d_in[15];
  const float* lnf_g = (const float*)d_in[16];
  const float* lnf_b = (const float*)d_in[17];
  const float* xm1_w = (const float*)d_in[18];
  const float* xm1_b = (const float*)d_in[19];
  const float* xm2_w = (const float*)d_in[20];
  const float* xm2_b = (const float*)d_in[21];
  const float* me1_w = (const float*)d_in[22];
  const float* me1_b = (const float*)d_in[23];
  const float* me2_w = (const float*)d_in[24];
  const float* me2_b = (const float*)d_in[25];
  const float* me3_w = (const float*)d_in[26];
  const float* me3_b = (const float*)d_in[27];

  const int M = BB * TT;  // 8192
  char* ws = (char*)d_ws;
  float*  X    = (float*)(ws);                        // 16 MB [8192,512] f32
  float*  PRJ  = (float*)(ws + ((size_t)16 << 20));   // 16 MB [8192,512] f32
  ushort* BIGp = (ushort*)(ws + ((size_t)32 << 20));  // 64 MB: QKV packs / FF pack
  ushort* PK1  = (ushort*)(ws + ((size_t)96 << 20));  // 16 MB: activation pack (2 planes)
  ushort* WSCR = (ushort*)(ws + ((size_t)112 << 20)); //  8 MB: weight packs
  float*  XM   = (float*)(ws + ((size_t)120 << 20));  // 512 KB [8192,16]
  float*  PART = (float*)(ws + ((size_t)121 << 20));  // 32 KB

  embed_kernel<<<M, 256, 0, stream>>>(u, y, W_in, b_in, X, PK1);

  for (int l = 0; l < LAYERS; ++l) {
    packL_kernel<<<2048, 256, 0, stream>>>(
        qkv_w + (size_t)l * 512 * 1536, out_w + (size_t)l * 512 * 512,
        ff1_w + (size_t)l * 512 * 2048, WSCR);
    gemm_mfma<0, 2, 128><<<dim3(12, 64), 256, 0, stream>>>(
        PK1, PK1 + PLANE_X, WSCR, WSCR + 786432, qkv_b + l * 1536,
        nullptr, nullptr, 0, BIGp, M, 1536, 512);
    attn_mfma<<<512, 256, 0, stream>>>(BIGp, PK1);
    gemm_mfma<0, 0, 64><<<dim3(4, 128), 256, 0, stream>>>(
        PK1, PK1 + PLANE_X, WSCR + 1572864, WSCR + 1835008, out_b + l * 512,
        PRJ, nullptr, 0, nullptr, M, 512, 512);
    ln_kernel<1><<<M, 128, 0, stream>>>(X, PRJ, ln1_g + l * 512, ln1_b + l * 512, X, PK1);
    gemm_mfma<1, 1, 128><<<dim3(16, 64), 256, 0, stream>>>(
        PK1, PK1 + PLANE_X, WSCR + 2097152, WSCR + 3145728, ff1_b + l * 2048,
        nullptr, BIGp, PLANE_FF, nullptr, M, 2048, 512);
    packF_kernel<<<1024, 256, 0, stream>>>(ff2_w + (size_t)l * 2048 * 512, WSCR);
    gemm_mfma<0, 0, 64><<<dim3(4, 128), 256, 0, stream>>>(
        BIGp, BIGp + PLANE_FF, WSCR, WSCR + 1048576, ff2_b + l * 512,
        PRJ, nullptr, 0, nullptr, M, 512, 2048);
    ln_kernel<1><<<M, 128, 0, stream>>>(X, PRJ, ln2_g + l * 512, ln2_b + l * 512, X, PK1);
  }
  ln_kernel<0><<<M, 128, 0, stream>>>(X, nullptr, lnf_g, lnf_b, X, PK1);

  packH_kernel<<<512, 256, 0, stream>>>(xm1_w, me2_w, WSCR);
  gemm_mfma<1, 0, 64><<<dim3(4, 128), 256, 0, stream>>>(
      PK1, PK1 + PLANE_X, WSCR, WSCR + 262144, xm1_b,
      PRJ, nullptr, 0, nullptr, M, 512, 512);
  gemm_bias<0, 0><<<dim3(1, 64), 256, 0, stream>>>(PRJ, xm2_w, xm2_b, XM, nullptr, 0, M, 16, 512);
  gemm_bias<1, 1><<<dim3(8, 64), 256, 0, stream>>>(XM, me1_w, me1_b, nullptr, PK1, PLANE_X, M, 512, 16);
  gemm_mfma<1, 0, 64><<<dim3(4, 128), 256, 0, stream>>>(
      PK1, PK1 + PLANE_X, WSCR + 524288, WSCR + 786432, me2_b,
      PRJ, nullptr, 0, nullptr, M, 512, 512);
  head_loss_kernel<<<M, 256, 0, stream>>>(PRJ, me3_w, me3_b, y, PART);
  reduce_kernel<<<1, 256, 0, stream>>>(PART, (float*)d_out, M);
}

// Round 8
// 1854.473 us; speedup vs baseline: 1.2285x; 1.2285x over previous
//
#include <hip/hip_runtime.h>
#include <cstdint>
#include <cstddef>

#define TT 2048
#define BB 4
#define HDIM 512
#define NH 4
#define LAYERS 4
#define WINDOW 606

#define PLANE_QK 4194304ull   // 16*2048*128
#define PLANE_X  4194304ull   // 8192*512
#define PLANE_FF 16777216ull  // 8192*2048

typedef __attribute__((ext_vector_type(8))) short bf16x8s;
typedef __attribute__((ext_vector_type(4))) float f32x4;

// ---------------- helpers ----------------
__device__ __forceinline__ float wred_sum(float v) {
#pragma unroll
  for (int off = 32; off; off >>= 1) v += __shfl_xor(v, off, 64);
  return v;
}
__device__ __forceinline__ float gelu_exact(float x) {
  return 0.5f * x * (1.0f + erff(x * 0.70710678118654752f));
}
__device__ __forceinline__ ushort bf16_rne(float v) {
  uint32_t u = __float_as_uint(v);
  u += 0x7FFFu + ((u >> 16) & 1u);
  return (ushort)(u >> 16);
}
__device__ __forceinline__ void split3(float v, ushort& h, ushort& l) {
  h = bf16_rne(v);
  const float hf = __uint_as_float(((uint32_t)h) << 16);
  l = bf16_rne(v - hf);
}
__device__ __forceinline__ void gld_lds16(const void* g, void* l) {
  __builtin_amdgcn_global_load_lds(
      (const __attribute__((address_space(1))) uint32_t*)g,
      (__attribute__((address_space(3))) uint32_t*)l, 16, 0, 0);
}

// ---------------- input embed ----------------
__global__ __launch_bounds__(256) void embed_kernel(
    const float* __restrict__ u, const float* __restrict__ y,
    const float* __restrict__ W_in, const float* __restrict__ b_in,
    float* __restrict__ X, ushort* __restrict__ xp) {
  const int row = blockIdx.x;
  const int b = row >> 11;
  const int t = row & 2047;
  const int tid = threadIdx.x;
  __shared__ float ua[24];
  if (tid < 8)       ua[tid] = u[((b << 3) + tid) * TT + t];
  else if (tid < 16) ua[tid] = 0.0f;   // y_aug (phy rollout) is zeros
  else if (tid < 24) ua[tid] = (t < 30) ? y[((b << 3) + (tid - 16)) * TT + t] : 0.0f;
  __syncthreads();
#pragma unroll
  for (int c0 = 0; c0 < 2; ++c0) {
    const int c = c0 * 256 + tid;
    float s = b_in[c];
#pragma unroll
    for (int k = 0; k < 24; ++k) s += ua[k] * W_in[k * HDIM + c];
    const float dv = expf(-0.0179889460337f * (float)(c & ~1));
    const float arg = (float)t * dv;
    s += (c & 1) ? cosf(arg) : sinf(arg);
    X[(size_t)row * HDIM + c] = s;
    ushort h, l2; split3(s, h, l2);
    xp[(size_t)row * HDIM + c] = h;
    xp[PLANE_X + (size_t)row * HDIM + c] = l2;
  }
}

// ---------------- weight pack ----------------
__device__ __forceinline__ void pack_tile(float (*tile)[33],
    const float* __restrict__ W, ushort* __restrict__ Wp,
    int K, int N, int bk, int bn, int tid) {
  const int i0 = tid >> 5, j = tid & 31;
#pragma unroll
  for (int i = 0; i < 4; ++i) {
    const int kk = i0 + i * 8;
    tile[kk][j] = W[(size_t)(bk + kk) * N + bn + j];
  }
  __syncthreads();
  const size_t NK = (size_t)N * K;
#pragma unroll
  for (int i = 0; i < 4; ++i) {
    const int nn = i0 + i * 8;
    const float v = tile[j][nn];
    ushort h, l2; split3(v, h, l2);
    ushort* base = Wp + (size_t)(bn + nn) * K + bk + j;
    base[0] = h; base[NK] = l2;
  }
}

__global__ __launch_bounds__(256) void packL_kernel(
    const float* __restrict__ qkvw, const float* __restrict__ outw,
    const float* __restrict__ ff1w, ushort* __restrict__ Wp) {
  __shared__ float tile[32][33];
  int i = blockIdx.x;
  if (i < 768) {
    pack_tile(tile, qkvw, Wp, 512, 1536, (i & 15) * 32, (i >> 4) * 32, threadIdx.x);
  } else if (i < 1024) {
    i -= 768;
    pack_tile(tile, outw, Wp + 1572864, 512, 512, (i & 15) * 32, (i >> 4) * 32, threadIdx.x);
  } else {
    i -= 1024;
    pack_tile(tile, ff1w, Wp + 2097152, 512, 2048, (i & 15) * 32, (i >> 4) * 32, threadIdx.x);
  }
}

__global__ __launch_bounds__(256) void packF_kernel(
    const float* __restrict__ ff2w, ushort* __restrict__ Wp) {
  __shared__ float tile[32][33];
  const int i = blockIdx.x;
  pack_tile(tile, ff2w, Wp, 2048, 512, (i & 63) * 32, (i >> 6) * 32, threadIdx.x);
}

__global__ __launch_bounds__(256) void packH_kernel(
    const float* __restrict__ xm1w, const float* __restrict__ me2w,
    ushort* __restrict__ Wp) {
  __shared__ float tile[32][33];
  int i = blockIdx.x;
  if (i < 256) pack_tile(tile, xm1w, Wp, 512, 512, (i & 15) * 32, (i >> 4) * 32, threadIdx.x);
  else { i -= 256; pack_tile(tile, me2w, Wp + 524288, 512, 512, (i & 15) * 32, (i >> 4) * 32, threadIdx.x); }
}

// ---------------- bf16 MFMA GEMM: 4-plane staging, all 3 terms per k-step ----------------
// A planes [M][K] (Ah, Al), B planes [N][K] (Bh, Bl). terms: Ah*Bh + Al*Bh + Ah*Bl.
// Per k-step: stage Ah,Al,Bh,Bl once (4 plane-stagings vs 6), 2 barriers (vs 6),
// 3*16*IA/4 MFMAs per barrier-pair. 1D grid, XCD-swizzled (grid%8==0).
template <int ACT, int OUTMODE, int RM>
__global__ __launch_bounds__(256) void gemm_mfma(
    const ushort* __restrict__ Ah, const ushort* __restrict__ Al,
    const ushort* __restrict__ Bh, const ushort* __restrict__ Bl,
    const float* __restrict__ bias,
    float* __restrict__ C, ushort* __restrict__ Cp, size_t cplane,
    ushort* __restrict__ Wq, int M, int N, int K, int nbn) {
  constexpr int IA = RM / 32;
  constexpr int JA = RM / 64;
  __shared__ ushort AlsH[RM * 32];
  __shared__ ushort AlsL[RM * 32];
  __shared__ ushort BlsH[4096];
  __shared__ ushort BlsL[4096];
  __shared__ float biasL[128];
  const int tid = threadIdx.x;
  // XCD swizzle: contiguous chunk of lids per XCD; bn fastest within chunk -> A-panel L2 reuse
  const int cpx = (int)gridDim.x >> 3;
  const int bid = blockIdx.x;
  const int lid = (bid & 7) * cpx + (bid >> 3);
  const int bn = (lid % nbn) * 128;
  const int bm = (lid / nbn) * RM;
  const int w = tid >> 6, ln = tid & 63;
  const int wr = (w >> 1) * (RM / 2), wc = (w & 1) * 64;
  const int c = ln & 15, g = ln >> 4;
  if (tid < 128) biasL[tid] = bias[bn + tid];
  const int srow = tid >> 2;
  const int scol = (tid & 3) * 8;

  f32x4 acc[IA][4] = {};
  for (int k0 = 0; k0 < K; k0 += 32) {
#pragma unroll
    for (int j = 0; j < JA; ++j) {
      const size_t ga = (size_t)(bm + j * 64 + srow) * K + k0 + scol;
      const int off = j * 4096 + tid * 16;
      gld_lds16(Ah + ga, (char*)AlsH + off);
      gld_lds16(Al + ga, (char*)AlsL + off);
    }
#pragma unroll
    for (int j = 0; j < 2; ++j) {
      const size_t gb = (size_t)(bn + j * 64 + srow) * K + k0 + scol;
      const int off = j * 4096 + tid * 16;
      gld_lds16(Bh + gb, (char*)BlsH + off);
      gld_lds16(Bl + gb, (char*)BlsL + off);
    }
    __syncthreads();
    bf16x8s fah[IA], fal[IA], fbh[4], fbl[4];
#pragma unroll
    for (int i = 0; i < IA; ++i) {
      const int ao = (wr + i * 16 + c) * 32 + g * 8;
      fah[i] = *(const bf16x8s*)&AlsH[ao];
      fal[i] = *(const bf16x8s*)&AlsL[ao];
    }
#pragma unroll
    for (int i = 0; i < 4; ++i) {
      const int bo = (wc + i * 16 + c) * 32 + g * 8;
      fbh[i] = *(const bf16x8s*)&BlsH[bo];
      fbl[i] = *(const bf16x8s*)&BlsL[bo];
    }
#pragma unroll
    for (int i = 0; i < IA; ++i)
#pragma unroll
      for (int j = 0; j < 4; ++j) {
        acc[i][j] = __builtin_amdgcn_mfma_f32_16x16x32_bf16(fah[i], fbh[j], acc[i][j], 0, 0, 0);
        acc[i][j] = __builtin_amdgcn_mfma_f32_16x16x32_bf16(fal[i], fbh[j], acc[i][j], 0, 0, 0);
        acc[i][j] = __builtin_amdgcn_mfma_f32_16x16x32_bf16(fah[i], fbl[j], acc[i][j], 0, 0, 0);
      }
    __syncthreads();
  }
  // epilogue: C/D layout col=lane&15, row=(lane>>4)*4+reg [m89-verified]
  // Q pre-scale folds 1/sqrt(128) * log2(e) so attention can use exp2.
  const float qscale = 0.08838834764831845f * 1.44269504088896341f;
#pragma unroll
  for (int i = 0; i < IA; ++i) {
    const int grow0 = bm + wr + i * 16 + g * 4;
#pragma unroll
    for (int j = 0; j < 4; ++j) {
      const int gcol = bn + wc + j * 16 + c;
      const float bv = biasL[wc + j * 16 + c];
      if (OUTMODE == 2) {
        const int bq = grow0 >> 11, tl = grow0 & 2047;
        if (bn < 512) {            // Q: scaled, row-major [bh][t][128]
          const int hh = gcol >> 7, d = gcol & 127;
          ushort* dst = Wq + ((size_t)(bq * NH + hh) * TT + tl) * 128 + d;
#pragma unroll
          for (int r = 0; r < 4; ++r) {
            ushort h, l2; split3((acc[i][j][r] + bv) * qscale, h, l2);
            dst[(size_t)r * 128] = h;
            dst[PLANE_QK + (size_t)r * 128] = l2;
          }
        } else if (bn < 1024) {    // K: row-major [bh][t][128]
          const int hh = (gcol - 512) >> 7, d = gcol & 127;
          ushort* dst = Wq + 2 * PLANE_QK + ((size_t)(bq * NH + hh) * TT + tl) * 128 + d;
#pragma unroll
          for (int r = 0; r < 4; ++r) {
            ushort h, l2; split3(acc[i][j][r] + bv, h, l2);
            dst[(size_t)r * 128] = h;
            dst[PLANE_QK + (size_t)r * 128] = l2;
          }
        } else {                   // V: transposed [bh][d][t]
          const int hh = (gcol - 1024) >> 7, d = gcol & 127;
          ushort4 h4, l4;
          split3(acc[i][j][0] + bv, h4.x, l4.x);
          split3(acc[i][j][1] + bv, h4.y, l4.y);
          split3(acc[i][j][2] + bv, h4.z, l4.z);
          split3(acc[i][j][3] + bv, h4.w, l4.w);
          ushort* dst = Wq + 4 * PLANE_QK + ((size_t)(bq * NH + hh) * 128 + d) * TT + tl;
          *(ushort4*)dst = h4;
          *(ushort4*)(dst + PLANE_QK) = l4;
        }
      } else {
#pragma unroll
        for (int r = 0; r < 4; ++r) {
          float v = acc[i][j][r] + bv;
          if (ACT) v = gelu_exact(v);
          if (OUTMODE == 1) {
            ushort h, l2; split3(v, h, l2);
            ushort* base = Cp + (size_t)(grow0 + r) * N + gcol;
            base[0] = h; base[cplane] = l2;
          } else {
            C[(size_t)(grow0 + r) * N + gcol] = v;
          }
        }
      }
    }
  }
}

// ---------------- fp32 tiled GEMM (small shapes: xm2, me1) ----------------
template <int ACT, int PACK>
__global__ __launch_bounds__(256) void gemm_bias(
    const float* __restrict__ A, const float* __restrict__ B,
    const float* __restrict__ bias, float* __restrict__ C,
    ushort* __restrict__ Cp, size_t cplane, int M, int N, int K) {
  __shared__ float As[16][132];
  __shared__ float Bs[16][64];
  const int bm = blockIdx.y * 128;
  const int bn = blockIdx.x * 64;
  const int tid = threadIdx.x;
  const int tx = tid & 15, ty = tid >> 4;
  float acc[8][4] = {};
  for (int k0 = 0; k0 < K; k0 += 16) {
#pragma unroll
    for (int i = 0; i < 8; ++i) {
      const int idx = i * 256 + tid;
      const int m = idx >> 4, k = idx & 15;
      As[k][m] = A[(size_t)(bm + m) * K + k0 + k];
    }
#pragma unroll
    for (int i = 0; i < 4; ++i) {
      const int idx = i * 256 + tid;
      const int k = idx >> 6, n = idx & 63;
      Bs[k][n] = (bn + n < N) ? B[(size_t)(k0 + k) * N + bn + n] : 0.0f;
    }
    __syncthreads();
#pragma unroll
    for (int kk = 0; kk < 16; ++kk) {
      float a[8], bb[4];
#pragma unroll
      for (int i = 0; i < 8; ++i) a[i] = As[kk][ty * 8 + i];
#pragma unroll
      for (int j = 0; j < 4; ++j) bb[j] = Bs[kk][tx * 4 + j];
#pragma unroll
      for (int i = 0; i < 8; ++i)
#pragma unroll
        for (int j = 0; j < 4; ++j) acc[i][j] += a[i] * bb[j];
    }
    __syncthreads();
  }
#pragma unroll
  for (int i = 0; i < 8; ++i) {
    const int m = bm + ty * 8 + i;
#pragma unroll
    for (int j = 0; j < 4; ++j) {
      const int n = bn + tx * 4 + j;
      if (n < N) {
        float v = acc[i][j] + bias[n];
        if (ACT) v = gelu_exact(v);
        if (PACK) {
          ushort h, l2; split3(v, h, l2);
          ushort* base = Cp + (size_t)m * N + n;
          base[0] = h; base[cplane] = l2;
        } else {
          C[(size_t)m * N + n] = v;
        }
      }
    }
  }
}

// ---------------- MFMA flash sliding-window attention (R4 variant, measured 140us) ----------------
// QKVp planes: Qh|Ql|Kh|Kl|Vth|Vtl, each PLANE_QK. Q/K: [bh][t][128]; Vt: [bh][d][t].
// Q pre-scaled by (1/sqrt(dh))*log2e -> exp2 softmax. Swapped-quadrant QK^T.
__global__ __launch_bounds__(256) void attn_mfma(
    const ushort* __restrict__ QKVp, ushort* __restrict__ atp) {
  // XCD-aware swizzle: 8 XCDs, 1024 blocks -> each XCD gets 2 full (b,h) q-ranges
  const int bid = blockIdx.x;
  const int lid = (bid & 7) * 128 + (bid >> 3);
  const int q0 = (lid & 63) * 32;
  const int bh = lid >> 6;
  const int b = bh >> 2, hh = bh & 3;
  const int tid = threadIdx.x;
  const int w = tid >> 6, lane = tid & 63;
  const int c = lane & 15, g = lane >> 4;
  const int wr = w >> 1, wc = w & 1;

  __shared__ ushort Ph[32][40], Pl[32][40];
  __shared__ float wmax[2][32], wsum[2][32];
  __shared__ float mrow[2][32], lrow[2][32];

  const ushort* Qh = QKVp;
  const ushort* Ql = QKVp + PLANE_QK;
  const ushort* Kh = QKVp + 2 * PLANE_QK;
  const ushort* Kl = QKVp + 3 * PLANE_QK;
  const ushort* Vh = QKVp + 4 * PLANE_QK;
  const ushort* Vl = QKVp + 5 * PLANE_QK;

  const size_t qkbase = (size_t)bh * TT * 128;
  const size_t vtbase = (size_t)bh * 128 * TT;

  // Q fragments (B-operand rows = q0 + wr*16 + c), held for the whole kernel
  bf16x8s qh[4], ql[4];
  {
    const ushort* qr = Qh + qkbase + (size_t)(q0 + wr * 16 + c) * 128 + g * 8;
    const ushort* qr2 = Ql + qkbase + (size_t)(q0 + wr * 16 + c) * 128 + g * 8;
#pragma unroll
    for (int kc = 0; kc < 4; ++kc) {
      qh[kc] = *(const bf16x8s*)(qr + kc * 32);
      ql[kc] = *(const bf16x8s*)(qr2 + kc * 32);
    }
  }

  if (tid < 32) { mrow[0][tid] = -1e30f; lrow[0][tid] = 0.0f; }
  __syncthreads();

  f32x4 oacc[2][2] = {};
  int par = 0;
  int lo_ = q0 - (WINDOW - 1); if (lo_ < 0) lo_ = 0;
  const int k_first = lo_ & ~31;
  const int qg = q0 + wr * 16 + c;       // this lane's query (for mask)
  const int qrow = wr * 16 + c;          // local row for softmax state

  for (int k0 = k_first; k0 <= q0; k0 += 32) {
    // V fragments (prefetch; consumed after barrier C)
    const bf16x8s vh0 = *(const bf16x8s*)(Vh + vtbase + (size_t)(w * 32 + c) * TT + k0 + g * 8);
    const bf16x8s vh1 = *(const bf16x8s*)(Vh + vtbase + (size_t)(w * 32 + 16 + c) * TT + k0 + g * 8);
    const bf16x8s vl0 = *(const bf16x8s*)(Vl + vtbase + (size_t)(w * 32 + c) * TT + k0 + g * 8);
    const bf16x8s vl1 = *(const bf16x8s*)(Vl + vtbase + (size_t)(w * 32 + 16 + c) * TT + k0 + g * 8);

    // scores (swapped): D[k_local][q_local]; wave quadrant k in [wc*16,..), q in [wr*16,..)
    f32x4 sacc = {};
    {
      const ushort* kr = Kh + qkbase + (size_t)(k0 + wc * 16 + c) * 128 + g * 8;
      const ushort* kr2 = Kl + qkbase + (size_t)(k0 + wc * 16 + c) * 128 + g * 8;
      bf16x8s kh[4], kl[4];
#pragma unroll
      for (int kc = 0; kc < 4; ++kc) {
        kh[kc] = *(const bf16x8s*)(kr + kc * 32);
        kl[kc] = *(const bf16x8s*)(kr2 + kc * 32);
      }
#pragma unroll
      for (int kc = 0; kc < 4; ++kc)
        sacc = __builtin_amdgcn_mfma_f32_16x16x32_bf16(kh[kc], qh[kc], sacc, 0, 0, 0);
#pragma unroll
      for (int kc = 0; kc < 4; ++kc)
        sacc = __builtin_amdgcn_mfma_f32_16x16x32_bf16(kl[kc], qh[kc], sacc, 0, 0, 0);
#pragma unroll
      for (int kc = 0; kc < 4; ++kc)
        sacc = __builtin_amdgcn_mfma_f32_16x16x32_bf16(kh[kc], ql[kc], sacc, 0, 0, 0);
    }
    // mask (lane's 4 regs = 4 consecutive k's, one q) + cheap row max
    float s[4];
    float m4 = -1e30f;
#pragma unroll
    for (int r = 0; r < 4; ++r) {
      const int kj = k0 + wc * 16 + g * 4 + r;
      const bool ok = (kj <= qg) && (kj > qg - WINDOW);
      s[r] = ok ? sacc[r] : -1e30f;
      m4 = fmaxf(m4, s[r]);
    }
    m4 = fmaxf(m4, __shfl_xor(m4, 16, 64));
    m4 = fmaxf(m4, __shfl_xor(m4, 32, 64));
    if (lane < 16) wmax[wc][qrow] = m4;
    __syncthreads();  // B

    // exp2 + P split to LDS + row sums
    {
      const float mt = fmaxf(wmax[0][qrow], wmax[1][qrow]);
      const float mn = fmaxf(mrow[par][qrow], mt);
      float pv[4];
      float ps = 0.0f;
#pragma unroll
      for (int r = 0; r < 4; ++r) {
        pv[r] = (s[r] > -1e29f) ? exp2f(s[r] - mn) : 0.0f;
        ps += pv[r];
      }
      ps += __shfl_xor(ps, 16, 64);
      ps += __shfl_xor(ps, 32, 64);
      if (lane < 16) wsum[wc][qrow] = ps;
      ushort4 h4, l4;
      split3(pv[0], h4.x, l4.x); split3(pv[1], h4.y, l4.y);
      split3(pv[2], h4.z, l4.z); split3(pv[3], h4.w, l4.w);
      *(ushort4*)&Ph[qrow][wc * 16 + g * 4] = h4;
      *(ushort4*)&Pl[qrow][wc * 16 + g * 4] = l4;
    }
    __syncthreads();  // C

    // m/l state update into par^1 (concurrent with PV below)
    if (tid < 32) {
      const float mt = fmaxf(wmax[0][tid], wmax[1][tid]);
      const float mo = mrow[par][tid];
      const float mn = fmaxf(mo, mt);
      mrow[par ^ 1][tid] = mn;
      lrow[par ^ 1][tid] = lrow[par][tid] * exp2f(mo - mn) + wsum[0][tid] + wsum[1][tid];
    }
    // PV: this wave owns output cols [w*32, w*32+32), all 32 rows
#pragma unroll
    for (int rh = 0; rh < 2; ++rh) {
      float sc[4];
#pragma unroll
      for (int r = 0; r < 4; ++r) {
        const int row = rh * 16 + g * 4 + r;
        const float mt = fmaxf(wmax[0][row], wmax[1][row]);
        const float mo = mrow[par][row];
        sc[r] = exp2f(mo - fmaxf(mo, mt));
      }
#pragma unroll
      for (int jt = 0; jt < 2; ++jt)
#pragma unroll
        for (int r = 0; r < 4; ++r) oacc[rh][jt][r] *= sc[r];
      const bf16x8s pah = *(const bf16x8s*)&Ph[rh * 16 + c][g * 8];
      const bf16x8s pal = *(const bf16x8s*)&Pl[rh * 16 + c][g * 8];
      oacc[rh][0] = __builtin_amdgcn_mfma_f32_16x16x32_bf16(pah, vh0, oacc[rh][0], 0, 0, 0);
      oacc[rh][0] = __builtin_amdgcn_mfma_f32_16x16x32_bf16(pal, vh0, oacc[rh][0], 0, 0, 0);
      oacc[rh][0] = __builtin_amdgcn_mfma_f32_16x16x32_bf16(pah, vl0, oacc[rh][0], 0, 0, 0);
      oacc[rh][1] = __builtin_amdgcn_mfma_f32_16x16x32_bf16(pah, vh1, oacc[rh][1], 0, 0, 0);
      oacc[rh][1] = __builtin_amdgcn_mfma_f32_16x16x32_bf16(pal, vh1, oacc[rh][1], 0, 0, 0);
      oacc[rh][1] = __builtin_amdgcn_mfma_f32_16x16x32_bf16(pah, vl1, oacc[rh][1], 0, 0, 0);
    }
    __syncthreads();  // D (protects Ph/Pl/wmax/wsum for next tile)
    par ^= 1;
  }

  // normalize + 2-plane pack out
#pragma unroll
  for (int rh = 0; rh < 2; ++rh) {
#pragma unroll
    for (int r = 0; r < 4; ++r) {
      const int row = rh * 16 + g * 4 + r;
      const float li = 1.0f / lrow[par][row];
      const int qgo = q0 + row;
      ushort* base = atp + (size_t)(b * TT + qgo) * HDIM + hh * 128;
#pragma unroll
      for (int jt = 0; jt < 2; ++jt) {
        const int d = w * 32 + jt * 16 + c;
        ushort h, l2; split3(oacc[rh][jt][r] * li, h, l2);
        base[d] = h;
        base[PLANE_X + d] = l2;
      }
    }
  }
}

// ---------------- residual + LayerNorm ----------------
template <int HAS_RES>
__global__ __launch_bounds__(128) void ln_kernel(
    const float* __restrict__ x, const float* __restrict__ r,
    const float* __restrict__ g, const float* __restrict__ be,
    float* __restrict__ out, ushort* __restrict__ xp) {
  const int row = blockIdx.x, tid = threadIdx.x;
  float4 v = ((const float4*)(x + (size_t)row * HDIM))[tid];
  if (HAS_RES) {
    const float4 rv = ((const float4*)(r + (size_t)row * HDIM))[tid];
    v.x += rv.x; v.y += rv.y; v.z += rv.z; v.w += rv.w;
  }
  __shared__ float red[2];
  float s = v.x + v.y + v.z + v.w;
  s = wred_sum(s);
  if ((tid & 63) == 0) red[tid >> 6] = s;
  __syncthreads();
  const float mean = (red[0] + red[1]) * (1.0f / 512.0f);
  const float dx = v.x - mean, dy = v.y - mean, dz = v.z - mean, dw = v.w - mean;
  float s2 = dx * dx + dy * dy + dz * dz + dw * dw;
  __syncthreads();
  s2 = wred_sum(s2);
  if ((tid & 63) == 0) red[tid >> 6] = s2;
  __syncthreads();
  const float var = (red[0] + red[1]) * (1.0f / 512.0f);
  const float inv = 1.0f / sqrtf(var + 1e-5f);
  const float4 gv = ((const float4*)g)[tid];
  const float4 bv = ((const float4*)be)[tid];
  float4 o;
  o.x = dx * inv * gv.x + bv.x;
  o.y = dy * inv * gv.y + bv.y;
  o.z = dz * inv * gv.z + bv.z;
  o.w = dw * inv * gv.w + bv.w;
  ((float4*)(out + (size_t)row * HDIM))[tid] = o;
  ushort4 h4, l4;
  split3(o.x, h4.x, l4.x); split3(o.y, h4.y, l4.y);
  split3(o.z, h4.z, l4.z); split3(o.w, h4.w, l4.w);
  ushort* basep = xp + (size_t)row * HDIM + tid * 4;
  *(ushort4*)basep = h4;
  *(ushort4*)(basep + PLANE_X) = l4;
}

// ---------------- fused me3 projection + SSE loss partials ----------------
__global__ __launch_bounds__(256) void head_loss_kernel(
    const float* __restrict__ hme, const float* __restrict__ w3,
    const float* __restrict__ b3, const float* __restrict__ y,
    float* __restrict__ partials) {
  const int row = blockIdx.x;
  const int b = row >> 11, t = row & 2047;
  const int tid = threadIdx.x;
  __shared__ __align__(16) float hl[512];
  __shared__ float acc8[8];
  ((float2*)hl)[tid] = ((const float2*)(hme + (size_t)row * HDIM))[tid];
  __syncthreads();
  const int d = tid >> 5, l32 = tid & 31;
  float s = 0.0f;
  for (int k = l32; k < 512; k += 32) s += hl[k] * w3[k * 8 + d];
#pragma unroll
  for (int off = 16; off; off >>= 1) s += __shfl_xor(s, off, 64);
  if (l32 == 0) {
    const float yh = s + b3[d];
    const float diff = yh - y[((b << 3) + d) * TT + t];
    acc8[d] = diff * diff;
  }
  __syncthreads();
  if (tid == 0) {
    float tot = 0.0f;
#pragma unroll
    for (int i = 0; i < 8; ++i) tot += acc8[i];
    partials[row] = tot;
  }
}

__global__ __launch_bounds__(256) void reduce_kernel(
    const float* __restrict__ partials, float* __restrict__ out, int n) {
  float s = 0.0f;
  for (int i = threadIdx.x; i < n; i += 256) s += partials[i];
  s = wred_sum(s);
  __shared__ float red[4];
  if ((threadIdx.x & 63) == 0) red[threadIdx.x >> 6] = s;
  __syncthreads();
  if (threadIdx.x == 0) out[0] = red[0] + red[1] + red[2] + red[3];
}

// ---------------- host ----------------
extern "C" void kernel_launch(void* const* d_in, const int* in_sizes, int n_in,
                              void* d_out, int out_size, void* d_ws, size_t ws_size,
                              hipStream_t stream) {
  (void)in_sizes; (void)n_in; (void)out_size; (void)ws_size;
  const float* u     = (const float*)d_in[0];
  const float* y     = (const float*)d_in[1];
  const float* W_in  = (const float*)d_in[2];
  const float* b_in  = (const float*)d_in[3];
  const float* qkv_w = (const float*)d_in[4];
  const float* qkv_b = (const float*)d_in[5];
  const float* out_w = (const float*)d_in[6];
  const float* out_b = (const float*)d_in[7];
  const float* ff1_w = (const float*)d_in[8];
  const float* ff1_b = (const float*)d_in[9];
  const float* ff2_w = (const float*)d_in[10];
  const float* ff2_b = (const float*)d_in[11];
  const float* ln1_g = (const float*)d_in[12];
  const float* ln1_b = (const float*)d_in[13];
  const float* ln2_g = (const float*)d_in[14];
  const float* ln2_b = (const float*)d_in[15];
  const float* lnf_g = (const float*)d_in[16];
  const float* lnf_b = (const float*)d_in[17];
  const float* xm1_w = (const float*)d_in[18];
  const float* xm1_b = (const float*)d_in[19];
  const float* xm2_w = (const float*)d_in[20];
  const float* xm2_b = (const float*)d_in[21];
  const float* me1_w = (const float*)d_in[22];
  const float* me1_b = (const float*)d_in[23];
  const float* me2_w = (const float*)d_in[24];
  const float* me2_b = (const float*)d_in[25];
  const float* me3_w = (const float*)d_in[26];
  const float* me3_b = (const float*)d_in[27];

  const int M = BB * TT;  // 8192
  char* ws = (char*)d_ws;
  float*  X    = (float*)(ws);                        // 16 MB [8192,512] f32
  float*  PRJ  = (float*)(ws + ((size_t)16 << 20));   // 16 MB [8192,512] f32
  ushort* BIGp = (ushort*)(ws + ((size_t)32 << 20));  // 64 MB: QKV packs / FF pack
  ushort* PK1  = (ushort*)(ws + ((size_t)96 << 20));  // 16 MB: activation pack (2 planes)
  ushort* WSCR = (ushort*)(ws + ((size_t)112 << 20)); //  8 MB: weight packs
  float*  XM   = (float*)(ws + ((size_t)120 << 20));  // 512 KB [8192,16]
  float*  PART = (float*)(ws + ((size_t)121 << 20));  // 32 KB

  embed_kernel<<<M, 256, 0, stream>>>(u, y, W_in, b_in, X, PK1);

  for (int l = 0; l < LAYERS; ++l) {
    packL_kernel<<<2048, 256, 0, stream>>>(
        qkv_w + (size_t)l * 512 * 1536, out_w + (size_t)l * 512 * 512,
        ff1_w + (size_t)l * 512 * 2048, WSCR);
    gemm_mfma<0, 2, 128><<<768, 256, 0, stream>>>(
        PK1, PK1 + PLANE_X, WSCR, WSCR + 786432, qkv_b + l * 1536,
        nullptr, nullptr, 0, BIGp, M, 1536, 512, 12);
    attn_mfma<<<1024, 256, 0, stream>>>(BIGp, PK1);
    gemm_mfma<0, 0, 64><<<512, 256, 0, stream>>>(
        PK1, PK1 + PLANE_X, WSCR + 1572864, WSCR + 1835008, out_b + l * 512,
        PRJ, nullptr, 0, nullptr, M, 512, 512, 4);
    ln_kernel<1><<<M, 128, 0, stream>>>(X, PRJ, ln1_g + l * 512, ln1_b + l * 512, X, PK1);
    gemm_mfma<1, 1, 128><<<1024, 256, 0, stream>>>(
        PK1, PK1 + PLANE_X, WSCR + 2097152, WSCR + 3145728, ff1_b + l * 2048,
        nullptr, BIGp, PLANE_FF, nullptr, M, 2048, 512, 16);
    packF_kernel<<<1024, 256, 0, stream>>>(ff2_w + (size_t)l * 2048 * 512, WSCR);
    gemm_mfma<0, 0, 64><<<512, 256, 0, stream>>>(
        BIGp, BIGp + PLANE_FF, WSCR, WSCR + 1048576, ff2_b + l * 512,
        PRJ, nullptr, 0, nullptr, M, 512, 2048, 4);
    ln_kernel<1><<<M, 128, 0, stream>>>(X, PRJ, ln2_g + l * 512, ln2_b + l * 512, X, PK1);
  }
  ln_kernel<0><<<M, 128, 0, stream>>>(X, nullptr, lnf_g, lnf_b, X, PK1);

  packH_kernel<<<512, 256, 0, stream>>>(xm1_w, me2_w, WSCR);
  gemm_mfma<1, 0, 64><<<512, 256, 0, stream>>>(
      PK1, PK1 + PLANE_X, WSCR, WSCR + 262144, xm1_b,
      PRJ, nullptr, 0, nullptr, M, 512, 512, 4);
  gemm_bias<0, 0><<<dim3(1, 64), 256, 0, stream>>>(PRJ, xm2_w, xm2_b, XM, nullptr, 0, M, 16, 512);
  gemm_bias<1, 1><<<dim3(8, 64), 256, 0, stream>>>(XM, me1_w, me1_b, nullptr, PK1, PLANE_X, M, 512, 16);
  gemm_mfma<1, 0, 64><<<512, 256, 0, stream>>>(
      PK1, PK1 + PLANE_X, WSCR + 524288, WSCR + 786432, me2_b,
      PRJ, nullptr, 0, nullptr, M, 512, 512, 4);
  head_loss_kernel<<<M, 256, 0, stream>>>(PRJ, me3_w, me3_b, y, PART);
  reduce_kernel<<<1, 256, 0, stream>>>(PART, (float*)d_out, M);
}